// Round 4
// baseline (11783.314 us; speedup 1.0000x reference)
//
#include <hip/hip_runtime.h>
#include <hip/hip_cooperative_groups.h>

namespace cg = cooperative_groups;

// Problem constants (from reference)
#define T_STEPS 100
#define BATCH   32
#define NIN     512
#define NN      2048
#define AREAS   2

// ALPHA = float(np.exp(-1e-3/1e-2)); cast to f32 at use-site (NEP-50 weak scalar).
#define ALPHA_D 0.9048374180359595

#define MW_WORDS (BATCH * 128)   // words per smask buffer

// ---------------------------------------------------------------------------
// k0: Poisson input spikes for ALL timesteps. f32 compare semantics.
// Writes f32 Xi to d_out[0..T*B*NIN) and per-(t,b) bitmasks
// xi_mask[(t*32+b)*16 + (i>>5)] bit (i&31) -> ascending-i walk per batch.
__global__ __launch_bounds__(256)
void k0_xi(const float* __restrict__ rates, const float* __restrict__ noise,
           float* __restrict__ outXi, unsigned* __restrict__ xi_mask)
{
    int el = blockIdx.x * 256 + threadIdx.x;      // exact grid: 1,638,400
    float r = rates[el], nz = noise[el];
    float p = __fmul_rn(r, 0.001f);
    int spike = (nz < p) ? 1 : 0;
    outXi[el] = (float)spike;
    if (spike) {
        int t = el >> 14;
        int b = (el >> 9) & 31;
        int i = el & (NIN - 1);
        atomicOr(&xi_mask[(t * 32 + b) * 16 + (i >> 5)], 1u << (i & 31));
    }
}

// ---------------------------------------------------------------------------
// k_ff v2: feedforward currents Iff[t][b][a][n], one block per (tb, a).
// No LDS weight tile (R3's version had 1.86e7 bank conflicts + 1 block/CU).
// Mask walk is block-uniform (no divergence); Win rows read coalesced from
// L2/L3 (8.4 MB, hot). Ascending-i pure f32 adds -> bit-exact vs numpy.
__global__ __launch_bounds__(256)
void k_ff(const float* __restrict__ Win, const unsigned* __restrict__ xi_mask,
          float* __restrict__ Iff)
{
    const int tb  = blockIdx.x;      // t*32+b, 0..3199
    const int a   = blockIdx.y;      // 0..1
    const int tid = threadIdx.x;     // covers cols [8*tid, 8*tid+8)

    __shared__ unsigned mws[16];
    if (tid < 16) mws[tid] = xi_mask[tb * 16 + tid];
    __syncthreads();

    const float* Wa = Win + ((size_t)a << 20) + (tid << 3);
    float4 A0 = {0,0,0,0}, A1 = {0,0,0,0};
    for (int w = 0; w < 16; ++w) {
        unsigned mw = mws[w];                   // block-uniform
        int base_i = w << 5;
        while (mw) {
            int i = base_i + (__ffs(mw) - 1);
            mw &= mw - 1;
            const float* rp = Wa + ((size_t)i << 11);
            float4 w0 = ((const float4*)rp)[0];
            float4 w1 = ((const float4*)rp)[1];
            A0.x += w0.x; A0.y += w0.y; A0.z += w0.z; A0.w += w0.w;
            A1.x += w1.x; A1.y += w1.y; A1.z += w1.z; A1.w += w1.w;
        }
    }
    float* op = Iff + (((size_t)tb * 2 + a) << 11) + (tid << 3);
    ((float4*)op)[0] = A0;
    ((float4*)op)[1] = A1;
}

// ---------------------------------------------------------------------------
// k_steps: PERSISTENT cooperative kernel, all 100 timesteps with grid.sync().
// 512 blocks x 256 = 2 blocks/CU co-resident. Block = (mc:8, b:32, a:2);
// thread owns one (a,b,m) column: V lives in a register for all 100 steps.
// Cross-block state = 3 rotating spike-mask buffers, accessed ONLY via
// agent-scope atomics (XCD L2s are not coherent for plain ld/st).
// Per-b active-row list built by wave-0 shuffle prefix-scan; gather is
// serial ascending (rr = s*2048+n == numpy einsum lex order) with 16
// outstanding loads for latency hiding (TLP is capped at 2 waves/SIMD).
__global__ __launch_bounds__(256, 2)
void k_steps(const float* __restrict__ Wrec,
             unsigned* __restrict__ smask,      // [3][B][128]
             const float* __restrict__ Iff,     // [t][b][a][n]
             float* __restrict__ outS)          // out + T*B*NIN
{
    cg::grid_group grid = cg::this_grid();
    const int tid = threadIdx.x;
    const int bx  = blockIdx.x;        // 0..511
    const int mc  = bx & 7;
    const int b   = (bx >> 3) & 31;
    const int a   = bx >> 8;
    const int m   = mc * 256 + tid;

    __shared__ unsigned short lrec[AREAS * NN];   // 8 KB
    __shared__ unsigned mws[128];
    __shared__ int base[128];
    __shared__ int cnt_rec;

    const float* __restrict__ Wr = Wrec + m;
    const int rr_self = (a << 11) | m;
    float v_state = 0.0f;

    for (int t = 0; t < T_STEPS; ++t) {
        unsigned* prev  = smask + (t % 3) * MW_WORDS;
        unsigned* next  = smask + ((t + 1) % 3) * MW_WORDS;
        unsigned* clear = smask + ((t + 2) % 3) * MW_WORDS;

        // zero the buffer that becomes `next` at step t+1 (4096 words/grid)
        if (tid < 8)
            __hip_atomic_store(&clear[bx * 8 + tid], 0u,
                               __ATOMIC_RELAXED, __HIP_MEMORY_SCOPE_AGENT);

        if (tid < 128)
            mws[tid] = __hip_atomic_load(&prev[b * 128 + tid],
                                         __ATOMIC_RELAXED, __HIP_MEMORY_SCOPE_AGENT);
        __syncthreads();

        if (tid < 64) {                  // wave-0 shuffle prefix scan
            int c0 = __popc(mws[2 * tid]), c1 = __popc(mws[2 * tid + 1]);
            int c = c0 + c1, incl = c;
            #pragma unroll
            for (int d = 1; d < 64; d <<= 1) {
                int v = __shfl_up(incl, d, 64);
                if (tid >= d) incl += v;
            }
            base[2 * tid]     = incl - c;
            base[2 * tid + 1] = incl - c1;
            if (tid == 63) cnt_rec = incl;
        }
        __syncthreads();
        if (tid < 128 && mws[tid]) {
            int off = base[tid];
            unsigned w = mws[tid];
            int bb = tid << 5;
            while (w) { int p = __ffs(w) - 1; lrec[off++] = (unsigned short)(bb + p); w &= w - 1; }
        }
        __syncthreads();

        const int nrec = cnt_rec;

        // ---- recurrent gather: ascending (s,n), serial f32 adds, ILP=16 ---
        float accr = 0.0f;
        int j = 0;
        for (; j + 16 <= nrec; j += 16) {
            const float* p[16];
            #pragma unroll
            for (int u = 0; u < 16; ++u) {
                int rr = lrec[j + u];
                p[u] = Wr + (((size_t)(rr >> 11) * 2 + a) << 22)
                          + ((size_t)(rr & (NN - 1)) << 11);
            }
            float w[16];
            #pragma unroll
            for (int u = 0; u < 16; ++u) w[u] = *p[u];
            #pragma unroll
            for (int u = 0; u < 16; ++u) accr = __fadd_rn(accr, w[u]);
        }
        for (; j < nrec; ++j) {
            int rr = lrec[j];
            accr = __fadd_rn(accr, Wr[(((size_t)(rr >> 11) * 2 + a) << 22)
                                      + ((size_t)(rr & (NN - 1)) << 11)]);
        }

        // ---- LIF update, numpy f32 op-for-op ----
        float accf = Iff[((((size_t)t * 32 + b) * 2 + a) << 11) + m];
        unsigned xd = (mws[rr_self >> 5] >> (rr_self & 31)) & 1u;
        float I  = __fadd_rn(accf, accr);
        float v  = __fmul_rn((float)ALPHA_D, v_state);
        if (xd) v = 0.0f;
        float vn = __fadd_rn(v, I);
        v_state = vn;
        int S = (vn >= 1.0f) ? 1 : 0;
        outS[(size_t)a * (T_STEPS * BATCH * NN) + (((size_t)t * BATCH + b) << 11) + m]
            = (float)S;
        if (S) atomicOr(&next[b * 128 + (rr_self >> 5)], 1u << (rr_self & 31));

        __threadfence();   // agent-scope release before the grid barrier
        grid.sync();
    }
}

// ---------------------------------------------------------------------------
extern "C" void kernel_launch(void* const* d_in, const int* in_sizes, int n_in,
                              void* d_out, int out_size, void* d_ws, size_t ws_size,
                              hipStream_t stream)
{
    const float* rates = (const float*)d_in[0];
    const float* noise = (const float*)d_in[1];
    const float* Win   = (const float*)d_in[2];
    const float* Wrec  = (const float*)d_in[3];
    float* out = (float*)d_out;

    // workspace layout (bytes):
    //   [0, 204800)          xi_mask uint32[T][B][16]
    //   [204800, 253952)     smask   uint32[3][B][128]
    //   [253952, +52428800)  Iff     float[T][B][A][N]
    char* ws = (char*)d_ws;
    unsigned* xi_mask = (unsigned*)ws;
    unsigned* smask   = (unsigned*)(ws + 204800);
    float*    Iff     = (float*)(ws + 253952);

    hipMemsetAsync(d_ws, 0, 253952, stream);    // zero xi_mask + 3 smask bufs

    k0_xi<<<6400, 256, 0, stream>>>(rates, noise, out, xi_mask);
    k_ff<<<dim3(3200, 2), 256, 0, stream>>>(Win, xi_mask, Iff);

    float* outS = out + (size_t)T_STEPS * BATCH * NIN;
    void* args[] = { (void*)&Wrec, (void*)&smask, (void*)&Iff, (void*)&outS };
    hipLaunchCooperativeKernel((const void*)k_steps, dim3(512), dim3(256),
                               args, 0, stream);
}

// Round 5
// 2070.884 us; speedup vs baseline: 5.6900x; 5.6900x over previous
//
#include <hip/hip_runtime.h>

// Problem constants (from reference)
#define T_STEPS 100
#define BATCH   32
#define NIN     512
#define NN      2048
#define AREAS   2

// ALPHA = float(np.exp(-1e-3/1e-2)); cast to f32 at use-site (NEP-50 weak scalar).
#define ALPHA_D 0.9048374180359595

// ---------------------------------------------------------------------------
// k0: Poisson input spikes for ALL timesteps. f32 compare semantics.
// Writes f32 Xi to d_out[0..T*B*NIN) and per-(t,b) bitmasks
// xi_mask[(t*32+b)*16 + (i>>5)] bit (i&31) -> ascending-i walk per batch.
__global__ __launch_bounds__(256)
void k0_xi(const float* __restrict__ rates, const float* __restrict__ noise,
           float* __restrict__ outXi, unsigned* __restrict__ xi_mask)
{
    int el = blockIdx.x * 256 + threadIdx.x;      // exact grid: 1,638,400
    float r = rates[el], nz = noise[el];
    float p = __fmul_rn(r, 0.001f);
    int spike = (nz < p) ? 1 : 0;
    outXi[el] = (float)spike;
    if (spike) {
        int t = el >> 14;
        int b = (el >> 9) & 31;
        int i = el & (NIN - 1);
        atomicOr(&xi_mask[(t * 32 + b) * 16 + (i >> 5)], 1u << (i & 31));
    }
}

// ---------------------------------------------------------------------------
// k_ff: feedforward currents Iff[t][b][a][n], one block per (tb, a).
// Global reads, no LDS weight tile (R3's LDS version: 1.86e7 bank conflicts,
// 1 block/CU). Mask walk is block-uniform (no divergence); Win rows read
// coalesced from L2/L3. Ascending-i pure f32 adds -> bit-exact vs numpy.
__global__ __launch_bounds__(256)
void k_ff(const float* __restrict__ Win, const unsigned* __restrict__ xi_mask,
          float* __restrict__ Iff)
{
    const int tb  = blockIdx.x;      // t*32+b, 0..3199
    const int a   = blockIdx.y;      // 0..1
    const int tid = threadIdx.x;     // covers cols [8*tid, 8*tid+8)

    __shared__ unsigned mws[16];
    if (tid < 16) mws[tid] = xi_mask[tb * 16 + tid];
    __syncthreads();

    const float* Wa = Win + ((size_t)a << 20) + (tid << 3);
    float4 A0 = {0,0,0,0}, A1 = {0,0,0,0};
    for (int w = 0; w < 16; ++w) {
        unsigned mw = mws[w];                   // block-uniform
        int base_i = w << 5;
        while (mw) {
            int i = base_i + (__ffs(mw) - 1);
            mw &= mw - 1;
            const float* rp = Wa + ((size_t)i << 11);
            float4 w0 = ((const float4*)rp)[0];
            float4 w1 = ((const float4*)rp)[1];
            A0.x += w0.x; A0.y += w0.y; A0.z += w0.z; A0.w += w0.w;
            A1.x += w1.x; A1.y += w1.y; A1.z += w1.z; A1.w += w1.w;
        }
    }
    float* op = Iff + (((size_t)tb * 2 + a) << 11) + (tid << 3);
    ((float4*)op)[0] = A0;
    ((float4*)op)[1] = A1;
}

// ---------------------------------------------------------------------------
// k_step: one launch per timestep, recurrent gather + LIF.
// grid (mc:8, b:32, a:2) x 256; bx%8 == mc -> all 64 (a,b) of a column chunk
// share an XCD L2 (union-row reuse). Per-b active list via wave-0 shuffle
// prefix scan (ascending rr = s*2048+n == numpy lex order). Gather is a
// manual 2-stage software pipeline in NAMED registers (R4's array version
// spilled to scratch: VGPR=28, 90 us/step of L2 churn): prefetch batch j+8
// while sequentially adding batch j. Bit-exact: add order is ascending.
__global__ __launch_bounds__(256)
void k_step(const float* __restrict__ Wrec,
            const unsigned* __restrict__ smask_prev,// [b*128 + w]
            unsigned* __restrict__ smask_next,
            unsigned* __restrict__ smask_clear,
            const float* __restrict__ Iff,          // [t][b][a][n]
            float* __restrict__ V,                  // f32 [A][B][N]
            float* __restrict__ outS,               // out + T*B*NIN
            int t)
{
    const int tid = threadIdx.x;
    const int mc  = blockIdx.x;      // 0..7
    const int b   = blockIdx.y;      // 0..31
    const int a   = blockIdx.z;      // 0..1
    const int m   = mc * 256 + tid;  // 0..2047

    // zero next-next-step mask buffer (512 blocks x 8 words = 4096)
    {
        int fb = ((a * 32 + b) * 8 + mc);
        if (tid < 8) smask_clear[fb * 8 + tid] = 0u;
    }

    __shared__ unsigned short lrec[AREAS * NN];   // 8 KB, 16B-aligned
    __shared__ unsigned mws[128];
    __shared__ int base[128];
    __shared__ int cnt_rec;

    if (tid < 128) mws[tid] = smask_prev[b * 128 + tid];
    __syncthreads();
    if (tid < 64) {                  // wave-0 shuffle prefix scan
        int c0 = __popc(mws[2 * tid]), c1 = __popc(mws[2 * tid + 1]);
        int c = c0 + c1, incl = c;
        #pragma unroll
        for (int d = 1; d < 64; d <<= 1) {
            int v = __shfl_up(incl, d, 64);
            if (tid >= d) incl += v;
        }
        base[2 * tid]     = incl - c;
        base[2 * tid + 1] = incl - c1;
        if (tid == 63) cnt_rec = incl;
    }
    __syncthreads();
    if (tid < 128 && mws[tid]) {
        int off = base[tid];
        unsigned w = mws[tid];
        int bb = tid << 5;
        while (w) { int p = __ffs(w) - 1; lrec[off++] = (unsigned short)(bb + p); w &= w - 1; }
    }
    __syncthreads();

    const int nrec = cnt_rec;

    // hoist state loads to overlap with the gather
    const int rr_self = (a << 11) | m;
    float accf = Iff[((((size_t)t * 32 + b) * 2 + a) << 11) + m];
    unsigned xd = (mws[rr_self >> 5] >> (rr_self & 31)) & 1u;
    int vi = ((a * 32) + b) * NN + m;
    float v_old = V[vi];

    // ---- recurrent gather: ascending (s,n), serial f32 adds --------------
    // element offset of row rr (col m folded into Wr base):
    //   off = ((rr>>11)*2 + a) * 2048*2048 + (rr&2047) * 2048   (< 2^24, int)
    const float* __restrict__ Wr = Wrec + m;
#define OFF_OF(rr) (((((rr) >> 11) * 2 + a) << 22) + (((rr) & 2047) << 11))

    float accr = 0.0f;
    int j = 0;
    if (nrec >= 8) {
        // prologue: load batch [0,8)
        uint4 u = *(const uint4*)&lrec[0];
        int o0 = OFF_OF((int)(u.x & 0xffff)), o1 = OFF_OF((int)(u.x >> 16));
        int o2 = OFF_OF((int)(u.y & 0xffff)), o3 = OFF_OF((int)(u.y >> 16));
        int o4 = OFF_OF((int)(u.z & 0xffff)), o5 = OFF_OF((int)(u.z >> 16));
        int o6 = OFF_OF((int)(u.w & 0xffff)), o7 = OFF_OF((int)(u.w >> 16));
        float p0 = Wr[o0], p1 = Wr[o1], p2 = Wr[o2], p3 = Wr[o3];
        float p4 = Wr[o4], p5 = Wr[o5], p6 = Wr[o6], p7 = Wr[o7];
        for (j = 8; j + 8 <= nrec; j += 8) {
            // prefetch batch [j, j+8)
            uint4 v = *(const uint4*)&lrec[j];
            int n0 = OFF_OF((int)(v.x & 0xffff)), n1 = OFF_OF((int)(v.x >> 16));
            int n2 = OFF_OF((int)(v.y & 0xffff)), n3 = OFF_OF((int)(v.y >> 16));
            int n4 = OFF_OF((int)(v.z & 0xffff)), n5 = OFF_OF((int)(v.z >> 16));
            int n6 = OFF_OF((int)(v.w & 0xffff)), n7 = OFF_OF((int)(v.w >> 16));
            float q0 = Wr[n0], q1 = Wr[n1], q2 = Wr[n2], q3 = Wr[n3];
            float q4 = Wr[n4], q5 = Wr[n5], q6 = Wr[n6], q7 = Wr[n7];
            // consume batch [j-8, j) strictly in order
            accr = __fadd_rn(accr, p0); accr = __fadd_rn(accr, p1);
            accr = __fadd_rn(accr, p2); accr = __fadd_rn(accr, p3);
            accr = __fadd_rn(accr, p4); accr = __fadd_rn(accr, p5);
            accr = __fadd_rn(accr, p6); accr = __fadd_rn(accr, p7);
            p0 = q0; p1 = q1; p2 = q2; p3 = q3;
            p4 = q4; p5 = q5; p6 = q6; p7 = q7;
        }
        // epilogue: consume last prefetched batch [j-8, j)
        accr = __fadd_rn(accr, p0); accr = __fadd_rn(accr, p1);
        accr = __fadd_rn(accr, p2); accr = __fadd_rn(accr, p3);
        accr = __fadd_rn(accr, p4); accr = __fadd_rn(accr, p5);
        accr = __fadd_rn(accr, p6); accr = __fadd_rn(accr, p7);
    }
    for (; j < nrec; ++j) {
        int rr = lrec[j];
        accr = __fadd_rn(accr, Wr[OFF_OF(rr)]);
    }
#undef OFF_OF

    // ---- LIF update, numpy f32 op-for-op ----
    float I  = __fadd_rn(accf, accr);
    float v  = __fmul_rn((float)ALPHA_D, v_old);
    if (xd) v = 0.0f;
    float vn = __fadd_rn(v, I);
    V[vi] = vn;
    int S = (vn >= 1.0f) ? 1 : 0;
    outS[(size_t)a * (T_STEPS * BATCH * NN) + (((size_t)t * BATCH + b) << 11) + m]
        = (float)S;
    if (S) atomicOr(&smask_next[b * 128 + (rr_self >> 5)], 1u << (rr_self & 31));
}

// ---------------------------------------------------------------------------
extern "C" void kernel_launch(void* const* d_in, const int* in_sizes, int n_in,
                              void* d_out, int out_size, void* d_ws, size_t ws_size,
                              hipStream_t stream)
{
    const float* rates = (const float*)d_in[0];
    const float* noise = (const float*)d_in[1];
    const float* Win   = (const float*)d_in[2];
    const float* Wrec  = (const float*)d_in[3];
    float* out = (float*)d_out;

    // workspace layout (bytes):
    //   [0, 204800)          xi_mask uint32[T][B][16]
    //   [204800, 253952)     smask   uint32[3][B][128]
    //   [253952, 778240)     V       float[A][B][N]
    //   [778240, +52428800)  Iff     float[T][B][A][N]
    char* ws = (char*)d_ws;
    unsigned* xi_mask = (unsigned*)ws;
    unsigned* smask   = (unsigned*)(ws + 204800);
    float*    V       = (float*)(ws + 253952);
    float*    Iff     = (float*)(ws + 778240);

    hipMemsetAsync(d_ws, 0, 778240, stream);    // zero masks + V

    k0_xi<<<6400, 256, 0, stream>>>(rates, noise, out, xi_mask);
    k_ff<<<dim3(3200, 2), 256, 0, stream>>>(Win, xi_mask, Iff);

    float* outS = out + (size_t)T_STEPS * BATCH * NIN;
    const int MW = BATCH * 128;                 // words per smask buffer
    for (int t = 0; t < T_STEPS; ++t) {
        unsigned* prev  = smask + (t % 3) * MW;
        unsigned* next  = smask + ((t + 1) % 3) * MW;
        unsigned* clear = smask + ((t + 2) % 3) * MW;
        k_step<<<dim3(8, 32, 2), 256, 0, stream>>>(
            Wrec, prev, next, clear, Iff, V, outS, t);
    }
}